// Round 7
// baseline (220.864 us; speedup 1.0000x reference)
//
#include <hip/hip_runtime.h>
#include <math.h>

#define LQ 512
#define CN 384
#define CE 128
#define CH 192
#define NG 12
#define PPG 16
#define FEAT 2112
#define NPROJ 1152

// ws float offsets
#define WS_RAW  0u        // [l][1152]: q(0..191) k(192..383) v(384..575) qv kv vv
#define WS_QVG  589824u   // [l][144] (row-major, q-side broadcast)
#define WS_KVT  663552u   // [144][512] transposed kv (j-major)
#define WS_VVG  737280u   // [l][288]
#define WS_QN   884736u   // [l][12]
#define WS_KNT  890880u   // [12][512] transposed kn
#define WS_KT   897024u   // [192][512] transposed k
#define WS_ATT  995328u   // [i][j][12] (unnormalized exp)
#define WS_FEAT 4141056u  // [i][2112]
#define WS_PART 5222400u  // [3][512][384] (k4/k5 only)
// partial-softmax stats live in the PART region (lifetime: k2->k3, before k4 writes)
#define WS_PM   WS_PART            // [i][q][12] partial max (q=0..3)
#define WS_PS   (WS_PART + 24576u) // [i][q][12] partial sum

// ---------------- K1a: tiled projection GEMM -> raw (+KT transposed copy) ----------------
__global__ __launch_bounds__(256) void k1a_gemm(
    const float* __restrict__ Node,
    const float* __restrict__ Wq, const float* __restrict__ Wk,
    const float* __restrict__ Wv, const float* __restrict__ Wqv,
    const float* __restrict__ Wkv, const float* __restrict__ Wvv,
    float* __restrict__ ws)
{
    __shared__ float As[64][68];
    __shared__ float Bs[64][48];
    const int tid = threadIdx.x;
    const int cb = blockIdx.x % 24;
    const int l0 = (blockIdx.x / 24) * 64;
    const int col0 = cb * 48;

    const float* W; int nc, lc0;
    if (col0 < 192)      { W = Wq;  nc = 192; lc0 = col0; }
    else if (col0 < 384) { W = Wk;  nc = 192; lc0 = col0 - 192; }
    else if (col0 < 576) { W = Wv;  nc = 192; lc0 = col0 - 384; }
    else if (col0 < 720) { W = Wqv; nc = 144; lc0 = col0 - 576; }
    else if (col0 < 864) { W = Wkv; nc = 144; lc0 = col0 - 720; }
    else                 { W = Wvv; nc = 288; lc0 = col0 - 864; }

    const int tx = tid & 15, ty = tid >> 4;
    float acc[4][3];
#pragma unroll
    for (int r = 0; r < 4; ++r)
#pragma unroll
        for (int c = 0; c < 3; ++c) acc[r][c] = 0.f;

    for (int kc = 0; kc < 6; ++kc) {
        __syncthreads();
#pragma unroll
        for (int pass = 0; pass < 4; ++pass) {
            int m = (tid >> 4) + pass * 16;
            int kk = (tid & 15) * 4;
            const float4 a = *(const float4*)(Node + (size_t)(l0 + m) * CN + kc * 64 + kk);
            As[kk + 0][m] = a.x; As[kk + 1][m] = a.y;
            As[kk + 2][m] = a.z; As[kk + 3][m] = a.w;
        }
#pragma unroll
        for (int p = 0; p < 12; ++p) {
            int idx = p * 256 + tid;
            int kk = idx / 48, c = idx - kk * 48;
            Bs[kk][c] = W[(size_t)(kc * 64 + kk) * nc + lc0 + c];
        }
        __syncthreads();
#pragma unroll 8
        for (int kk = 0; kk < 64; ++kk) {
            const float4 av = *(const float4*)&As[kk][tx * 4];
            const float b0 = Bs[kk][ty * 3 + 0];
            const float b1 = Bs[kk][ty * 3 + 1];
            const float b2 = Bs[kk][ty * 3 + 2];
            acc[0][0] = fmaf(av.x, b0, acc[0][0]); acc[0][1] = fmaf(av.x, b1, acc[0][1]); acc[0][2] = fmaf(av.x, b2, acc[0][2]);
            acc[1][0] = fmaf(av.y, b0, acc[1][0]); acc[1][1] = fmaf(av.y, b1, acc[1][1]); acc[1][2] = fmaf(av.y, b2, acc[1][2]);
            acc[2][0] = fmaf(av.z, b0, acc[2][0]); acc[2][1] = fmaf(av.z, b1, acc[2][1]); acc[2][2] = fmaf(av.z, b2, acc[2][2]);
            acc[3][0] = fmaf(av.w, b0, acc[3][0]); acc[3][1] = fmaf(av.w, b1, acc[3][1]); acc[3][2] = fmaf(av.w, b2, acc[3][2]);
        }
    }
    float* raw = ws + WS_RAW;
#pragma unroll
    for (int r = 0; r < 4; ++r)
#pragma unroll
        for (int c = 0; c < 3; ++c)
            raw[(size_t)(l0 + tx * 4 + r) * NPROJ + col0 + ty * 3 + c] = acc[r][c];
    // transposed copy of the k block for coalesced j-major reads in k2
    if (col0 >= 192 && col0 < 384) {
#pragma unroll
        for (int r = 0; r < 4; ++r)
#pragma unroll
            for (int c = 0; c < 3; ++c)
                ws[WS_KT + (size_t)(col0 - 192 + ty * 3 + c) * LQ + l0 + tx * 4 + r] = acc[r][c];
    }
}

// ---------------- K1b: frame apply + point norms (kv/kn stored transposed) ----------------
__global__ __launch_bounds__(256) void k1b_vec(
    const float* __restrict__ rots, const float* __restrict__ trans,
    float* __restrict__ ws)
{
    __shared__ float sqbuf[96];
    const int tid = threadIdx.x;
    const int l = blockIdx.x;
    const float* raw = ws + WS_RAW + (size_t)l * NPROJ;

    if (tid < 192) {
        int src, pt, typ;
        if (tid < 48)      { typ = 0; pt = tid;      src = 576 + pt * 3; }
        else if (tid < 96) { typ = 1; pt = tid - 48; src = 720 + pt * 3; }
        else               { typ = 2; pt = tid - 96; src = 864 + pt * 3; }
        float v0 = raw[src], v1 = raw[src + 1], v2 = raw[src + 2];
        const float* R = rots + l * 9;
        float o0 = R[0] * v0 + R[1] * v1 + R[2] * v2 + trans[l * 3 + 0] * 0.1f;
        float o1 = R[3] * v0 + R[4] * v1 + R[5] * v2 + trans[l * 3 + 1] * 0.1f;
        float o2 = R[6] * v0 + R[7] * v1 + R[8] * v2 + trans[l * 3 + 2] * 0.1f;
        if (typ == 0) {
            float* dst = ws + WS_QVG + (size_t)l * 144 + pt * 3;
            dst[0] = o0; dst[1] = o1; dst[2] = o2;
        } else if (typ == 1) {
            ws[WS_KVT + (size_t)(pt * 3 + 0) * LQ + l] = o0;
            ws[WS_KVT + (size_t)(pt * 3 + 1) * LQ + l] = o1;
            ws[WS_KVT + (size_t)(pt * 3 + 2) * LQ + l] = o2;
        } else {
            float* dst = ws + WS_VVG + (size_t)l * 288 + pt * 3;
            dst[0] = o0; dst[1] = o1; dst[2] = o2;
        }
        if (tid < 96) sqbuf[tid] = o0 * o0 + o1 * o1 + o2 * o2;
    }
    __syncthreads();
    if (tid < 24) {
        int typ = tid / 12, g = tid % 12;
        int b = typ * 48 + g * 4;
        float s = sqbuf[b] + sqbuf[b + 1] + sqbuf[b + 2] + sqbuf[b + 3];
        if (typ == 0) ws[WS_QN + (size_t)l * 12 + g] = s;
        else          ws[WS_KNT + (size_t)g * LQ + l] = s;
    }
}

// ---------------- K2: logits + partial softmax (j-split x4, reg-prefetch staging) ----------------
__global__ __launch_bounds__(128, 4) void k2_attn(
    const float* __restrict__ Edge, const float* __restrict__ Wbias,
    const float* __restrict__ gamma, float* __restrict__ ws)
{
    __shared__ float et[128 * 33];    // 16.9 KB
    __shared__ float wbs[CE * NG];    // 6 KB
    __shared__ float qls[CH], qvls[144], qnls[NG], cgls[NG];
    __shared__ float red[2][NG];
    const int tid = threadIdx.x;
    const int i = blockIdx.x >> 2;
    const int q = blockIdx.x & 3;
    const int j = q * 128 + tid;

    for (int u = tid; u < CE * NG; u += 128) wbs[u] = Wbias[u];
    for (int u = tid; u < CH; u += 128)  qls[u]  = ws[WS_RAW + (size_t)i * NPROJ + u];
    for (int u = tid; u < 144; u += 128) qvls[u] = ws[WS_QVG + (size_t)i * 144 + u];
    if (tid < NG) {
        qnls[tid] = ws[WS_QN + (size_t)i * NG + tid];
        cgls[tid] = log1pf(__expf(gamma[tid])) * 0.11785113019775793f; // softplus*WC/2
    }
    __syncthreads();

    // base logits: q.k/4 - cg*sq — all K-side reads j-major (coalesced)
    float lgs[NG];
    {
        const float* KT  = ws + WS_KT;
        const float* KVT = ws + WS_KVT;
        const float* KNT = ws + WS_KNT;
#pragma unroll
        for (int g = 0; g < NG; ++g) {
            float qk = 0.f;
#pragma unroll
            for (int u = 0; u < PPG; ++u)
                qk = fmaf(qls[g * PPG + u], KT[(size_t)(g * PPG + u) * LQ + j], qk);
            float dt = 0.f;
#pragma unroll
            for (int u = 0; u < 12; ++u)
                dt = fmaf(qvls[g * 12 + u], KVT[(size_t)(g * 12 + u) * LQ + j], dt);
            float sq = qnls[g] + KNT[(size_t)g * LQ + j] - 2.f * dt;
            lgs[g] = qk * 0.25f - cgls[g] * sq;
        }
    }

    // bias: 4 chunks of 32 channels; register-prefetch chunk ch+1 under compute of ch
    const float4* ebase = (const float4*)Edge + ((size_t)i * LQ + q * 128) * 32;
    float4 buf[8];
#pragma unroll
    for (int p = 0; p < 8; ++p) {
        int idx = p * 128 + tid;             // 0..1023
        int jr = idx >> 3, c4 = idx & 7;
        buf[p] = ebase[(size_t)jr * 32 + c4];
    }
    for (int ch = 0; ch < 4; ++ch) {
        __syncthreads();
#pragma unroll
        for (int p = 0; p < 8; ++p) {
            int idx = p * 128 + tid;
            int jr = idx >> 3, c4 = idx & 7;
            float4 v = buf[p];
            float* d = et + jr * 33 + c4 * 4;
            d[0] = v.x; d[1] = v.y; d[2] = v.z; d[3] = v.w;
        }
        __syncthreads();
        if (ch < 3) {
#pragma unroll
            for (int p = 0; p < 8; ++p) {
                int idx = p * 128 + tid;
                int jr = idx >> 3, c4 = idx & 7;
                buf[p] = ebase[(size_t)jr * 32 + (ch + 1) * 8 + c4];
            }
        }
        const float* wbch = wbs + ch * 32 * NG;
        const float* r0 = et + tid * 33;
#pragma unroll 4
        for (int c = 0; c < 32; ++c) {
            float e0 = r0[c];
            const float* wb = wbch + c * NG;
#pragma unroll
            for (int g = 0; g < NG; ++g) lgs[g] = fmaf(e0, wb[g], lgs[g]);
        }
    }

    // partial softmax over this block's 128 keys (2 waves)
    const float WL = 0.5773502691896258f;
    const int wid = tid >> 6, lane = tid & 63;
    float pm[NG];
#pragma unroll
    for (int g = 0; g < NG; ++g) pm[g] = lgs[g];
#pragma unroll
    for (int g = 0; g < NG; ++g)
        for (int off = 1; off < 64; off <<= 1)
            pm[g] = fmaxf(pm[g], __shfl_xor(pm[g], off));
    if (lane == 0) {
#pragma unroll
        for (int g = 0; g < NG; ++g) red[wid][g] = pm[g];
    }
    __syncthreads();
    float gm[NG];
#pragma unroll
    for (int g = 0; g < NG; ++g) gm[g] = fmaxf(red[0][g], red[1][g]);
    if (tid < NG)
        ws[WS_PM + ((size_t)i * 4 + q) * NG + tid] = fmaxf(red[0][tid], red[1][tid]);
    __syncthreads();

    float ps[NG];
#pragma unroll
    for (int g = 0; g < NG; ++g) {
        float e = __expf(WL * (lgs[g] - gm[g]));
        lgs[g] = e;
        ps[g] = e;
    }
#pragma unroll
    for (int g = 0; g < NG; ++g)
        for (int off = 1; off < 64; off <<= 1)
            ps[g] += __shfl_xor(ps[g], off);
    if (lane == 0) {
#pragma unroll
        for (int g = 0; g < NG; ++g) red[wid][g] = ps[g];
    }
    __syncthreads();
    if (tid < NG)
        ws[WS_PS + ((size_t)i * 4 + q) * NG + tid] = red[0][tid] + red[1][tid];

    // store unnormalized exp values
    float4* dst = (float4*)(ws + WS_ATT + ((size_t)i * LQ + j) * NG);
    float4 s0, s1, s2;
    s0.x = lgs[0]; s0.y = lgs[1]; s0.z = lgs[2];  s0.w = lgs[3];
    s1.x = lgs[4]; s1.y = lgs[5]; s1.z = lgs[6];  s1.w = lgs[7];
    s2.x = lgs[8]; s2.y = lgs[9]; s2.z = lgs[10]; s2.w = lgs[11];
    dst[0] = s0; dst[1] = s1; dst[2] = s2;
}

// ---------------- K3: O_Edge / O_Node / O_vec / O_norm -> feat ----------------
__global__ __launch_bounds__(256) void k3_out(
    const float* __restrict__ Edge, const float* __restrict__ rots,
    const float* __restrict__ trans, float* __restrict__ ws)
{
    __shared__ float at[LQ][13];
    __shared__ float bufA[4][32][NG][4];
    __shared__ float ovec[288];
    __shared__ float sc[4][NG];
    const int tid = threadIdx.x;
    const int qi = blockIdx.x;
    const float* att = ws + WS_ATT + (size_t)qi * LQ * NG;

    // merge 4 partial softmax stats -> per-quarter scale
    if (tid < 48) {
        const float WL = 0.5773502691896258f;
        int hh = tid / NG, g = tid % NG;
        float m0 = ws[WS_PM + ((size_t)qi * 4 + 0) * NG + g];
        float m1 = ws[WS_PM + ((size_t)qi * 4 + 1) * NG + g];
        float m2 = ws[WS_PM + ((size_t)qi * 4 + 2) * NG + g];
        float m3 = ws[WS_PM + ((size_t)qi * 4 + 3) * NG + g];
        float s0 = ws[WS_PS + ((size_t)qi * 4 + 0) * NG + g];
        float s1 = ws[WS_PS + ((size_t)qi * 4 + 1) * NG + g];
        float s2 = ws[WS_PS + ((size_t)qi * 4 + 2) * NG + g];
        float s3 = ws[WS_PS + ((size_t)qi * 4 + 3) * NG + g];
        float m = fmaxf(fmaxf(m0, m1), fmaxf(m2, m3));
        float e0 = __expf(WL * (m0 - m));
        float e1 = __expf(WL * (m1 - m));
        float e2 = __expf(WL * (m2 - m));
        float e3 = __expf(WL * (m3 - m));
        float denom = s0 * e0 + s1 * e1 + s2 * e2 + s3 * e3;
        float eh = (hh == 0) ? e0 : (hh == 1) ? e1 : (hh == 2) ? e2 : e3;
        sc[hh][g] = eh / denom;
    }
    __syncthreads();

    for (int m = 0; m < 2; ++m) {
        int j = tid + m * 256;
        int hh = j >> 7;
        const float4* src = (const float4*)(att + (size_t)j * NG);
        float4 a = src[0], b = src[1], c = src[2];
        at[j][0] = a.x * sc[hh][0]; at[j][1] = a.y * sc[hh][1];
        at[j][2] = a.z * sc[hh][2]; at[j][3] = a.w * sc[hh][3];
        at[j][4] = b.x * sc[hh][4]; at[j][5] = b.y * sc[hh][5];
        at[j][6] = b.z * sc[hh][6]; at[j][7] = b.w * sc[hh][7];
        at[j][8] = c.x * sc[hh][8]; at[j][9] = c.y * sc[hh][9];
        at[j][10] = c.z * sc[hh][10]; at[j][11] = c.w * sc[hh][11];
    }
    __syncthreads();

    // Phase A: O_Edge
    const int w = tid >> 6, lane = tid & 63, jh = lane >> 5, c4 = lane & 31;
    float acc[NG][4];
#pragma unroll
    for (int g = 0; g < NG; ++g)
#pragma unroll
        for (int r = 0; r < 4; ++r) acc[g][r] = 0.f;
    const float4* e4 = (const float4*)(Edge + (size_t)qi * LQ * CE);
    for (int jj = 0; jj < 64; ++jj) {
        int j = w * 128 + jh * 64 + jj;
        float4 e = e4[(size_t)j * 32 + c4];
#pragma unroll
        for (int g = 0; g < NG; ++g) {
            float a = at[j][g];
            acc[g][0] = fmaf(a, e.x, acc[g][0]);
            acc[g][1] = fmaf(a, e.y, acc[g][1]);
            acc[g][2] = fmaf(a, e.z, acc[g][2]);
            acc[g][3] = fmaf(a, e.w, acc[g][3]);
        }
    }
#pragma unroll
    for (int g = 0; g < NG; ++g)
#pragma unroll
        for (int r = 0; r < 4; ++r) acc[g][r] += __shfl_xor(acc[g][r], 32);
    if (jh == 0) {
#pragma unroll
        for (int g = 0; g < NG; ++g)
#pragma unroll
            for (int r = 0; r < 4; ++r) bufA[w][c4][g][r] = acc[g][r];
    }
    __syncthreads();
    float* feat = ws + WS_FEAT + (size_t)qi * FEAT;
    for (int m = 0; m < 6; ++m) {
        int o = tid + m * 256;
        int g = o >> 7, c = o & 127;
        int cc4 = c >> 2, r = c & 3;
        feat[o] = bufA[0][cc4][g][r] + bufA[1][cc4][g][r] +
                  bufA[2][cc4][g][r] + bufA[3][cc4][g][r];
    }

    // Phase B: O_Node + O_vec(global)
    const float* raw = ws + WS_RAW;
    const float* vvg = ws + WS_VVG;
    for (int ph = 0; ph < 2; ++ph) {
        int task = tid + ph * 256;
        if (task < 192) {
            int g = task >> 4;
            float s = 0.f;
            for (int j = 0; j < LQ; ++j) s = fmaf(at[j][g], raw[(size_t)j * NPROJ + 384 + task], s);
            feat[1536 + task] = s;
        } else if (task < 480) {
            int u = task - 192;
            int g = u / 24;
            float s = 0.f;
            for (int j = 0; j < LQ; ++j) s = fmaf(at[j][g], vvg[(size_t)j * 288 + u], s);
            ovec[u] = s;
        }
    }
    __syncthreads();

    // Phase C: inverse frame + norms
    if (tid < 96) {
        int g = tid >> 3, p = tid & 7;
        const float* R = rots + qi * 9;
        float t0 = trans[qi * 3 + 0] * 0.1f;
        float t1 = trans[qi * 3 + 1] * 0.1f;
        float t2 = trans[qi * 3 + 2] * 0.1f;
        float d0 = ovec[g * 24 + p * 3 + 0] - t0;
        float d1 = ovec[g * 24 + p * 3 + 1] - t1;
        float d2 = ovec[g * 24 + p * 3 + 2] - t2;
        float o0 = R[0] * d0 + R[3] * d1 + R[6] * d2;
        float o1 = R[1] * d0 + R[4] * d1 + R[7] * d2;
        float o2 = R[2] * d0 + R[5] * d1 + R[8] * d2;
        feat[1728 + g * 24 + p * 3 + 0] = o0;
        feat[1728 + g * 24 + p * 3 + 1] = o1;
        feat[1728 + g * 24 + p * 3 + 2] = o2;
        feat[2016 + g * 8 + p] = sqrtf(o0 * o0 + o1 * o1 + o2 * o2 + 1e-8f);
    }
}

// ---------------- K4: feat @ Wout — LDS-tiled GEMM, split-K x3 ----------------
__global__ __launch_bounds__(256) void k4_gemm(const float* __restrict__ Wout,
                                               float* __restrict__ ws)
{
    __shared__ float As[64][68];
    __shared__ float Bs[64][48];
    const int tid = threadIdx.x;
    const int cc = blockIdx.x >> 6;          // split-K index 0..2
    const int t  = blockIdx.x & 63;
    const int l0 = (t >> 3) * 64;
    const int col0 = (t & 7) * 48;
    const float* feat = ws + WS_FEAT;

    const int tx = tid & 15, ty = tid >> 4;
    float acc[4][3];
#pragma unroll
    for (int r = 0; r < 4; ++r)
#pragma unroll
        for (int c = 0; c < 3; ++c) acc[r][c] = 0.f;

    for (int kc = cc * 11; kc < cc * 11 + 11; ++kc) {
        __syncthreads();
#pragma unroll
        for (int pass = 0; pass < 4; ++pass) {
            int m = (tid >> 4) + pass * 16;
            int kk = (tid & 15) * 4;
            const float4 a = *(const float4*)(feat + (size_t)(l0 + m) * FEAT + kc * 64 + kk);
            As[kk + 0][m] = a.x; As[kk + 1][m] = a.y;
            As[kk + 2][m] = a.z; As[kk + 3][m] = a.w;
        }
#pragma unroll
        for (int p = 0; p < 12; ++p) {
            int idx = p * 256 + tid;
            int kk = idx / 48, c = idx - kk * 48;
            Bs[kk][c] = Wout[(size_t)(kc * 64 + kk) * CN + col0 + c];
        }
        __syncthreads();
#pragma unroll 8
        for (int kk = 0; kk < 64; ++kk) {
            const float4 av = *(const float4*)&As[kk][tx * 4];
            const float b0 = Bs[kk][ty * 3 + 0];
            const float b1 = Bs[kk][ty * 3 + 1];
            const float b2 = Bs[kk][ty * 3 + 2];
            acc[0][0] = fmaf(av.x, b0, acc[0][0]); acc[0][1] = fmaf(av.x, b1, acc[0][1]); acc[0][2] = fmaf(av.x, b2, acc[0][2]);
            acc[1][0] = fmaf(av.y, b0, acc[1][0]); acc[1][1] = fmaf(av.y, b1, acc[1][1]); acc[1][2] = fmaf(av.y, b2, acc[1][2]);
            acc[2][0] = fmaf(av.z, b0, acc[2][0]); acc[2][1] = fmaf(av.z, b1, acc[2][1]); acc[2][2] = fmaf(av.z, b2, acc[2][2]);
            acc[3][0] = fmaf(av.w, b0, acc[3][0]); acc[3][1] = fmaf(av.w, b1, acc[3][1]); acc[3][2] = fmaf(av.w, b2, acc[3][2]);
        }
    }
    float* part = ws + WS_PART + (size_t)cc * LQ * CN;
#pragma unroll
    for (int r = 0; r < 4; ++r)
#pragma unroll
        for (int c = 0; c < 3; ++c)
            part[(size_t)(l0 + tx * 4 + r) * CN + col0 + ty * 3 + c] = acc[r][c];
}

// ---------------- K5: reduce partials + bias ----------------
__global__ __launch_bounds__(384) void k5_red(const float* __restrict__ bout,
                                              const float* __restrict__ wsc,
                                              float* __restrict__ out)
{
    const int i = blockIdx.x, n = threadIdx.x;
    const float* part = wsc + WS_PART;
    size_t idx = (size_t)i * CN + n;
    size_t st = (size_t)LQ * CN;
    out[idx] = part[idx] + part[st + idx] + part[2 * st + idx] + bout[n];
}

extern "C" void kernel_launch(void* const* d_in, const int* in_sizes, int n_in,
                              void* d_out, int out_size, void* d_ws, size_t ws_size,
                              hipStream_t stream) {
    const float* Node  = (const float*)d_in[0];
    const float* Edge  = (const float*)d_in[1];
    const float* rots  = (const float*)d_in[2];
    const float* trans = (const float*)d_in[3];
    const float* Wq    = (const float*)d_in[4];
    const float* Wk    = (const float*)d_in[5];
    const float* Wv    = (const float*)d_in[6];
    const float* Wqv   = (const float*)d_in[7];
    const float* Wkv   = (const float*)d_in[8];
    const float* Wvv   = (const float*)d_in[9];
    const float* Wbias = (const float*)d_in[10];
    const float* gamma = (const float*)d_in[11];
    const float* Wout  = (const float*)d_in[12];
    const float* bout  = (const float*)d_in[13];
    float* ws = (float*)d_ws;

    k1a_gemm<<<192, 256, 0, stream>>>(Node, Wq, Wk, Wv, Wqv, Wkv, Wvv, ws);
    k1b_vec<<<512, 256, 0, stream>>>(rots, trans, ws);
    k2_attn<<<2048, 128, 0, stream>>>(Edge, Wbias, gamma, ws);
    k3_out<<<512, 256, 0, stream>>>(Edge, rots, trans, ws);
    k4_gemm<<<192, 256, 0, stream>>>(Wout, ws);
    k5_red<<<512, 384, 0, stream>>>(bout, ws, (float*)d_out);
}

// Round 8
// 201.984 us; speedup vs baseline: 1.0935x; 1.0935x over previous
//
#include <hip/hip_runtime.h>
#include <math.h>

#define LQ 512
#define CN 384
#define CE 128
#define CH 192
#define NG 12
#define PPG 16
#define FEAT 2112
#define NPROJ 1152

// ws float offsets
#define WS_RAW  0u        // [l][1152]: q(0..191) k(192..383) v(384..575) qv kv vv
#define WS_QVG  589824u   // [l][144] (row-major, q-side broadcast)
#define WS_KVT  663552u   // [144][512] transposed kv (j-major)
#define WS_VVG  737280u   // [l][288]
#define WS_QN   884736u   // [l][12]
#define WS_KNT  890880u   // [12][512] transposed kn
#define WS_KT   897024u   // [192][512] transposed k
#define WS_ATT  995328u   // [i][j][12] (unnormalized exp)
#define WS_FEAT 4141056u  // [i][2112]
#define WS_PART 5222400u  // [3][512][384] (k4/k5 only)
// partial-softmax stats live in the PART region (lifetime: k2->k3, before k4 writes)
#define WS_PM   WS_PART            // [i][h][12] partial max (h=0..1)
#define WS_PS   (WS_PART + 12288u) // [i][h][12] partial sum

// ---------------- K1a: tiled projection GEMM -> raw (+KT transposed copy) ----------------
__global__ __launch_bounds__(256) void k1a_gemm(
    const float* __restrict__ Node,
    const float* __restrict__ Wq, const float* __restrict__ Wk,
    const float* __restrict__ Wv, const float* __restrict__ Wqv,
    const float* __restrict__ Wkv, const float* __restrict__ Wvv,
    float* __restrict__ ws)
{
    __shared__ float As[64][68];
    __shared__ float Bs[64][48];
    const int tid = threadIdx.x;
    const int cb = blockIdx.x % 24;
    const int l0 = (blockIdx.x / 24) * 64;
    const int col0 = cb * 48;

    const float* W; int nc, lc0;
    if (col0 < 192)      { W = Wq;  nc = 192; lc0 = col0; }
    else if (col0 < 384) { W = Wk;  nc = 192; lc0 = col0 - 192; }
    else if (col0 < 576) { W = Wv;  nc = 192; lc0 = col0 - 384; }
    else if (col0 < 720) { W = Wqv; nc = 144; lc0 = col0 - 576; }
    else if (col0 < 864) { W = Wkv; nc = 144; lc0 = col0 - 720; }
    else                 { W = Wvv; nc = 288; lc0 = col0 - 864; }

    const int tx = tid & 15, ty = tid >> 4;
    float acc[4][3];
#pragma unroll
    for (int r = 0; r < 4; ++r)
#pragma unroll
        for (int c = 0; c < 3; ++c) acc[r][c] = 0.f;

    for (int kc = 0; kc < 6; ++kc) {
        __syncthreads();
#pragma unroll
        for (int pass = 0; pass < 4; ++pass) {
            int m = (tid >> 4) + pass * 16;
            int kk = (tid & 15) * 4;
            const float4 a = *(const float4*)(Node + (size_t)(l0 + m) * CN + kc * 64 + kk);
            As[kk + 0][m] = a.x; As[kk + 1][m] = a.y;
            As[kk + 2][m] = a.z; As[kk + 3][m] = a.w;
        }
#pragma unroll
        for (int p = 0; p < 12; ++p) {
            int idx = p * 256 + tid;
            int kk = idx / 48, c = idx - kk * 48;
            Bs[kk][c] = W[(size_t)(kc * 64 + kk) * nc + lc0 + c];
        }
        __syncthreads();
#pragma unroll 8
        for (int kk = 0; kk < 64; ++kk) {
            const float4 av = *(const float4*)&As[kk][tx * 4];
            const float b0 = Bs[kk][ty * 3 + 0];
            const float b1 = Bs[kk][ty * 3 + 1];
            const float b2 = Bs[kk][ty * 3 + 2];
            acc[0][0] = fmaf(av.x, b0, acc[0][0]); acc[0][1] = fmaf(av.x, b1, acc[0][1]); acc[0][2] = fmaf(av.x, b2, acc[0][2]);
            acc[1][0] = fmaf(av.y, b0, acc[1][0]); acc[1][1] = fmaf(av.y, b1, acc[1][1]); acc[1][2] = fmaf(av.y, b2, acc[1][2]);
            acc[2][0] = fmaf(av.z, b0, acc[2][0]); acc[2][1] = fmaf(av.z, b1, acc[2][1]); acc[2][2] = fmaf(av.z, b2, acc[2][2]);
            acc[3][0] = fmaf(av.w, b0, acc[3][0]); acc[3][1] = fmaf(av.w, b1, acc[3][1]); acc[3][2] = fmaf(av.w, b2, acc[3][2]);
        }
    }
    float* raw = ws + WS_RAW;
#pragma unroll
    for (int r = 0; r < 4; ++r)
#pragma unroll
        for (int c = 0; c < 3; ++c)
            raw[(size_t)(l0 + tx * 4 + r) * NPROJ + col0 + ty * 3 + c] = acc[r][c];
    // transposed copy of the k block for coalesced j-major reads in k2
    if (col0 >= 192 && col0 < 384) {
#pragma unroll
        for (int r = 0; r < 4; ++r)
#pragma unroll
            for (int c = 0; c < 3; ++c)
                ws[WS_KT + (size_t)(col0 - 192 + ty * 3 + c) * LQ + l0 + tx * 4 + r] = acc[r][c];
    }
}

// ---------------- K1b: frame apply + point norms (kv/kn stored transposed) ----------------
__global__ __launch_bounds__(256) void k1b_vec(
    const float* __restrict__ rots, const float* __restrict__ trans,
    float* __restrict__ ws)
{
    __shared__ float sqbuf[96];
    const int tid = threadIdx.x;
    const int l = blockIdx.x;
    const float* raw = ws + WS_RAW + (size_t)l * NPROJ;

    if (tid < 192) {
        int src, pt, typ;
        if (tid < 48)      { typ = 0; pt = tid;      src = 576 + pt * 3; }
        else if (tid < 96) { typ = 1; pt = tid - 48; src = 720 + pt * 3; }
        else               { typ = 2; pt = tid - 96; src = 864 + pt * 3; }
        float v0 = raw[src], v1 = raw[src + 1], v2 = raw[src + 2];
        const float* R = rots + l * 9;
        float o0 = R[0] * v0 + R[1] * v1 + R[2] * v2 + trans[l * 3 + 0] * 0.1f;
        float o1 = R[3] * v0 + R[4] * v1 + R[5] * v2 + trans[l * 3 + 1] * 0.1f;
        float o2 = R[6] * v0 + R[7] * v1 + R[8] * v2 + trans[l * 3 + 2] * 0.1f;
        if (typ == 0) {
            float* dst = ws + WS_QVG + (size_t)l * 144 + pt * 3;
            dst[0] = o0; dst[1] = o1; dst[2] = o2;
        } else if (typ == 1) {
            ws[WS_KVT + (size_t)(pt * 3 + 0) * LQ + l] = o0;
            ws[WS_KVT + (size_t)(pt * 3 + 1) * LQ + l] = o1;
            ws[WS_KVT + (size_t)(pt * 3 + 2) * LQ + l] = o2;
        } else {
            float* dst = ws + WS_VVG + (size_t)l * 288 + pt * 3;
            dst[0] = o0; dst[1] = o1; dst[2] = o2;
        }
        if (tid < 96) sqbuf[tid] = o0 * o0 + o1 * o1 + o2 * o2;
    }
    __syncthreads();
    if (tid < 24) {
        int typ = tid / 12, g = tid % 12;
        int b = typ * 48 + g * 4;
        float s = sqbuf[b] + sqbuf[b + 1] + sqbuf[b + 2] + sqbuf[b + 3];
        if (typ == 0) ws[WS_QN + (size_t)l * 12 + g] = s;
        else          ws[WS_KNT + (size_t)g * LQ + l] = s;
    }
}

// ---------------- K2: logits + partial softmax ----------------
// Wave-uniform operands (Wbias, q-side) read from GLOBAL (scalar s_load path),
// only lane-varying Edge tile goes through LDS -> LDS pipe unthrottled.
__global__ __launch_bounds__(256, 4) void k2_attn(
    const float* __restrict__ Edge, const float* __restrict__ Wbias,
    const float* __restrict__ gamma, float* __restrict__ ws)
{
    __shared__ float et[256 * 33];    // 33.8 KB
    __shared__ float cgls[NG];
    __shared__ float red[4][NG];
    const int tid = threadIdx.x;
    const int i = blockIdx.x >> 1;
    const int h = blockIdx.x & 1;
    const int j = h * 256 + tid;

    if (tid < NG)
        cgls[tid] = log1pf(__expf(gamma[tid])) * 0.11785113019775793f; // softplus*WC/2
    __syncthreads();

    // base logits: q.k/4 - cg*sq — q-side uniform (scalar), K-side j-major (coalesced vector)
    float lgs[NG];
    {
        const float* qrow  = ws + WS_RAW + (size_t)i * NPROJ;      // uniform
        const float* qvrow = ws + WS_QVG + (size_t)i * 144;        // uniform
        const float* qnrow = ws + WS_QN  + (size_t)i * NG;         // uniform
        const float* KT  = ws + WS_KT;
        const float* KVT = ws + WS_KVT;
        const float* KNT = ws + WS_KNT;
#pragma unroll
        for (int g = 0; g < NG; ++g) {
            float qk = 0.f;
#pragma unroll
            for (int u = 0; u < PPG; ++u)
                qk = fmaf(qrow[g * PPG + u], KT[(size_t)(g * PPG + u) * LQ + j], qk);
            float dt = 0.f;
#pragma unroll
            for (int u = 0; u < 12; ++u)
                dt = fmaf(qvrow[g * 12 + u], KVT[(size_t)(g * 12 + u) * LQ + j], dt);
            float sq = qnrow[g] + KNT[(size_t)g * LQ + j] - 2.f * dt;
            lgs[g] = qk * 0.25f - cgls[g] * sq;
        }
    }

    // bias: 4 chunks of 32 channels, Edge LDS-staged; Wbias scalar from global
    const float4* e4 = (const float4*)Edge + ((size_t)i * LQ + h * 256) * 32;
    for (int ch = 0; ch < 4; ++ch) {
        __syncthreads();
#pragma unroll
        for (int kk = 0; kk < 8; ++kk) {
            int idx = kk * 256 + tid;        // 0..2047
            int jr = idx >> 3, c4 = idx & 7;
            float4 v = e4[(size_t)jr * 32 + ch * 8 + c4];
            float* d = et + jr * 33 + c4 * 4;
            d[0] = v.x; d[1] = v.y; d[2] = v.z; d[3] = v.w;
        }
        __syncthreads();
        const float* wbch = Wbias + ch * 32 * NG;   // uniform -> s_load
        const float* r0 = et + tid * 33;
#pragma unroll 4
        for (int c = 0; c < 32; ++c) {
            float e0 = r0[c];
            const float* wb = wbch + c * NG;
#pragma unroll
            for (int g = 0; g < NG; ++g) lgs[g] = fmaf(e0, wb[g], lgs[g]);
        }
    }

    // partial softmax over this block's 256 keys
    const float WL = 0.5773502691896258f;
    const int wid = tid >> 6, lane = tid & 63;
    float pm[NG];
#pragma unroll
    for (int g = 0; g < NG; ++g) pm[g] = lgs[g];
#pragma unroll
    for (int g = 0; g < NG; ++g)
        for (int off = 1; off < 64; off <<= 1)
            pm[g] = fmaxf(pm[g], __shfl_xor(pm[g], off));
    if (lane == 0) {
#pragma unroll
        for (int g = 0; g < NG; ++g) red[wid][g] = pm[g];
    }
    __syncthreads();
    float gm[NG];
#pragma unroll
    for (int g = 0; g < NG; ++g)
        gm[g] = fmaxf(fmaxf(red[0][g], red[1][g]), fmaxf(red[2][g], red[3][g]));
    if (tid < NG)
        ws[WS_PM + ((size_t)i * 2 + h) * NG + tid] =
            fmaxf(fmaxf(red[0][tid], red[1][tid]), fmaxf(red[2][tid], red[3][tid]));
    __syncthreads();

    float ps[NG];
#pragma unroll
    for (int g = 0; g < NG; ++g) {
        float e = __expf(WL * (lgs[g] - gm[g]));
        lgs[g] = e;
        ps[g] = e;
    }
#pragma unroll
    for (int g = 0; g < NG; ++g)
        for (int off = 1; off < 64; off <<= 1)
            ps[g] += __shfl_xor(ps[g], off);
    if (lane == 0) {
#pragma unroll
        for (int g = 0; g < NG; ++g) red[wid][g] = ps[g];
    }
    __syncthreads();
    if (tid < NG)
        ws[WS_PS + ((size_t)i * 2 + h) * NG + tid] =
            red[0][tid] + red[1][tid] + red[2][tid] + red[3][tid];

    // store unnormalized exp values
    float4* dst = (float4*)(ws + WS_ATT + ((size_t)i * LQ + j) * NG);
    float4 s0, s1, s2;
    s0.x = lgs[0]; s0.y = lgs[1]; s0.z = lgs[2];  s0.w = lgs[3];
    s1.x = lgs[4]; s1.y = lgs[5]; s1.z = lgs[6];  s1.w = lgs[7];
    s2.x = lgs[8]; s2.y = lgs[9]; s2.z = lgs[10]; s2.w = lgs[11];
    dst[0] = s0; dst[1] = s1; dst[2] = s2;
}

// ---------------- K3: O_Edge / O_Node / O_vec / O_norm -> feat ----------------
__global__ __launch_bounds__(256) void k3_out(
    const float* __restrict__ Edge, const float* __restrict__ rots,
    const float* __restrict__ trans, float* __restrict__ ws)
{
    __shared__ float at[LQ][13];
    __shared__ float bufA[4][32][NG][4];
    __shared__ float ovec[288];
    __shared__ float sc[2][NG];
    const int tid = threadIdx.x;
    const int qi = blockIdx.x;
    const float* att = ws + WS_ATT + (size_t)qi * LQ * NG;

    // merge partial softmax stats -> per-half scale
    if (tid < 24) {
        const float WL = 0.5773502691896258f;
        int hh = tid / NG, g = tid % NG;
        float m0 = ws[WS_PM + ((size_t)qi * 2 + 0) * NG + g];
        float m1 = ws[WS_PM + ((size_t)qi * 2 + 1) * NG + g];
        float ss0 = ws[WS_PS + ((size_t)qi * 2 + 0) * NG + g];
        float ss1 = ws[WS_PS + ((size_t)qi * 2 + 1) * NG + g];
        float m = fmaxf(m0, m1);
        float e0 = __expf(WL * (m0 - m));
        float e1 = __expf(WL * (m1 - m));
        float denom = ss0 * e0 + ss1 * e1;
        sc[hh][g] = (hh ? e1 : e0) / denom;
    }
    __syncthreads();

    for (int m = 0; m < 2; ++m) {
        int j = tid + m * 256;
        int hh = j >> 8;
        const float4* src = (const float4*)(att + (size_t)j * NG);
        float4 a = src[0], b = src[1], c = src[2];
        at[j][0] = a.x * sc[hh][0]; at[j][1] = a.y * sc[hh][1];
        at[j][2] = a.z * sc[hh][2]; at[j][3] = a.w * sc[hh][3];
        at[j][4] = b.x * sc[hh][4]; at[j][5] = b.y * sc[hh][5];
        at[j][6] = b.z * sc[hh][6]; at[j][7] = b.w * sc[hh][7];
        at[j][8] = c.x * sc[hh][8]; at[j][9] = c.y * sc[hh][9];
        at[j][10] = c.z * sc[hh][10]; at[j][11] = c.w * sc[hh][11];
    }
    __syncthreads();

    // Phase A: O_Edge
    const int w = tid >> 6, lane = tid & 63, jh = lane >> 5, c4 = lane & 31;
    float acc[NG][4];
#pragma unroll
    for (int g = 0; g < NG; ++g)
#pragma unroll
        for (int r = 0; r < 4; ++r) acc[g][r] = 0.f;
    const float4* e4 = (const float4*)(Edge + (size_t)qi * LQ * CE);
    for (int jj = 0; jj < 64; ++jj) {
        int j = w * 128 + jh * 64 + jj;
        float4 e = e4[(size_t)j * 32 + c4];
#pragma unroll
        for (int g = 0; g < NG; ++g) {
            float a = at[j][g];
            acc[g][0] = fmaf(a, e.x, acc[g][0]);
            acc[g][1] = fmaf(a, e.y, acc[g][1]);
            acc[g][2] = fmaf(a, e.z, acc[g][2]);
            acc[g][3] = fmaf(a, e.w, acc[g][3]);
        }
    }
#pragma unroll
    for (int g = 0; g < NG; ++g)
#pragma unroll
        for (int r = 0; r < 4; ++r) acc[g][r] += __shfl_xor(acc[g][r], 32);
    if (jh == 0) {
#pragma unroll
        for (int g = 0; g < NG; ++g)
#pragma unroll
            for (int r = 0; r < 4; ++r) bufA[w][c4][g][r] = acc[g][r];
    }
    __syncthreads();
    float* feat = ws + WS_FEAT + (size_t)qi * FEAT;
    for (int m = 0; m < 6; ++m) {
        int o = tid + m * 256;
        int g = o >> 7, c = o & 127;
        int cc4 = c >> 2, r = c & 3;
        feat[o] = bufA[0][cc4][g][r] + bufA[1][cc4][g][r] +
                  bufA[2][cc4][g][r] + bufA[3][cc4][g][r];
    }

    // Phase B: O_Node + O_vec(global)
    const float* raw = ws + WS_RAW;
    const float* vvg = ws + WS_VVG;
    for (int ph = 0; ph < 2; ++ph) {
        int task = tid + ph * 256;
        if (task < 192) {
            int g = task >> 4;
            float s = 0.f;
            for (int j = 0; j < LQ; ++j) s = fmaf(at[j][g], raw[(size_t)j * NPROJ + 384 + task], s);
            feat[1536 + task] = s;
        } else if (task < 480) {
            int u = task - 192;
            int g = u / 24;
            float s = 0.f;
            for (int j = 0; j < LQ; ++j) s = fmaf(at[j][g], vvg[(size_t)j * 288 + u], s);
            ovec[u] = s;
        }
    }
    __syncthreads();

    // Phase C: inverse frame + norms
    if (tid < 96) {
        int g = tid >> 3, p = tid & 7;
        const float* R = rots + qi * 9;
        float t0 = trans[qi * 3 + 0] * 0.1f;
        float t1 = trans[qi * 3 + 1] * 0.1f;
        float t2 = trans[qi * 3 + 2] * 0.1f;
        float d0 = ovec[g * 24 + p * 3 + 0] - t0;
        float d1 = ovec[g * 24 + p * 3 + 1] - t1;
        float d2 = ovec[g * 24 + p * 3 + 2] - t2;
        float o0 = R[0] * d0 + R[3] * d1 + R[6] * d2;
        float o1 = R[1] * d0 + R[4] * d1 + R[7] * d2;
        float o2 = R[2] * d0 + R[5] * d1 + R[8] * d2;
        feat[1728 + g * 24 + p * 3 + 0] = o0;
        feat[1728 + g * 24 + p * 3 + 1] = o1;
        feat[1728 + g * 24 + p * 3 + 2] = o2;
        feat[2016 + g * 8 + p] = sqrtf(o0 * o0 + o1 * o1 + o2 * o2 + 1e-8f);
    }
}

// ---------------- K4: feat @ Wout — LDS-tiled GEMM, split-K x3 ----------------
__global__ __launch_bounds__(256) void k4_gemm(const float* __restrict__ Wout,
                                               float* __restrict__ ws)
{
    __shared__ float As[64][68];
    __shared__ float Bs[64][48];
    const int tid = threadIdx.x;
    const int cc = blockIdx.x >> 6;          // split-K index 0..2
    const int t  = blockIdx.x & 63;
    const int l0 = (t >> 3) * 64;
    const int col0 = (t & 7) * 48;
    const float* feat = ws + WS_FEAT;

    const int tx = tid & 15, ty = tid >> 4;
    float acc[4][3];
#pragma unroll
    for (int r = 0; r < 4; ++r)
#pragma unroll
        for (int c = 0; c < 3; ++c) acc[r][c] = 0.f;

    for (int kc = cc * 11; kc < cc * 11 + 11; ++kc) {
        __syncthreads();
#pragma unroll
        for (int pass = 0; pass < 4; ++pass) {
            int m = (tid >> 4) + pass * 16;
            int kk = (tid & 15) * 4;
            const float4 a = *(const float4*)(feat + (size_t)(l0 + m) * FEAT + kc * 64 + kk);
            As[kk + 0][m] = a.x; As[kk + 1][m] = a.y;
            As[kk + 2][m] = a.z; As[kk + 3][m] = a.w;
        }
#pragma unroll
        for (int p = 0; p < 12; ++p) {
            int idx = p * 256 + tid;
            int kk = idx / 48, c = idx - kk * 48;
            Bs[kk][c] = Wout[(size_t)(kc * 64 + kk) * CN + col0 + c];
        }
        __syncthreads();
#pragma unroll 8
        for (int kk = 0; kk < 64; ++kk) {
            const float4 av = *(const float4*)&As[kk][tx * 4];
            const float b0 = Bs[kk][ty * 3 + 0];
            const float b1 = Bs[kk][ty * 3 + 1];
            const float b2 = Bs[kk][ty * 3 + 2];
            acc[0][0] = fmaf(av.x, b0, acc[0][0]); acc[0][1] = fmaf(av.x, b1, acc[0][1]); acc[0][2] = fmaf(av.x, b2, acc[0][2]);
            acc[1][0] = fmaf(av.y, b0, acc[1][0]); acc[1][1] = fmaf(av.y, b1, acc[1][1]); acc[1][2] = fmaf(av.y, b2, acc[1][2]);
            acc[2][0] = fmaf(av.z, b0, acc[2][0]); acc[2][1] = fmaf(av.z, b1, acc[2][1]); acc[2][2] = fmaf(av.z, b2, acc[2][2]);
            acc[3][0] = fmaf(av.w, b0, acc[3][0]); acc[3][1] = fmaf(av.w, b1, acc[3][1]); acc[3][2] = fmaf(av.w, b2, acc[3][2]);
        }
    }
    float* part = ws + WS_PART + (size_t)cc * LQ * CN;
#pragma unroll
    for (int r = 0; r < 4; ++r)
#pragma unroll
        for (int c = 0; c < 3; ++c)
            part[(size_t)(l0 + tx * 4 + r) * CN + col0 + ty * 3 + c] = acc[r][c];
}

// ---------------- K5: reduce partials + bias ----------------
__global__ __launch_bounds__(384) void k5_red(const float* __restrict__ bout,
                                              const float* __restrict__ wsc,
                                              float* __restrict__ out)
{
    const int i = blockIdx.x, n = threadIdx.x;
    const float* part = wsc + WS_PART;
    size_t idx = (size_t)i * CN + n;
    size_t st = (size_t)LQ * CN;
    out[idx] = part[idx] + part[st + idx] + part[2 * st + idx] + bout[n];
}

extern "C" void kernel_launch(void* const* d_in, const int* in_sizes, int n_in,
                              void* d_out, int out_size, void* d_ws, size_t ws_size,
                              hipStream_t stream) {
    const float* Node  = (const float*)d_in[0];
    const float* Edge  = (const float*)d_in[1];
    const float* rots  = (const float*)d_in[2];
    const float* trans = (const float*)d_in[3];
    const float* Wq    = (const float*)d_in[4];
    const float* Wk    = (const float*)d_in[5];
    const float* Wv    = (const float*)d_in[6];
    const float* Wqv   = (const float*)d_in[7];
    const float* Wkv   = (const float*)d_in[8];
    const float* Wvv   = (const float*)d_in[9];
    const float* Wbias = (const float*)d_in[10];
    const float* gamma = (const float*)d_in[11];
    const float* Wout  = (const float*)d_in[12];
    const float* bout  = (const float*)d_in[13];
    float* ws = (float*)d_ws;

    k1a_gemm<<<192, 256, 0, stream>>>(Node, Wq, Wk, Wv, Wqv, Wkv, Wvv, ws);
    k1b_vec<<<512, 256, 0, stream>>>(rots, trans, ws);
    k2_attn<<<1024, 256, 0, stream>>>(Edge, Wbias, gamma, ws);
    k3_out<<<512, 256, 0, stream>>>(Edge, rots, trans, ws);
    k4_gemm<<<192, 256, 0, stream>>>(Wout, ws);
    k5_red<<<512, 384, 0, stream>>>(bout, ws, (float*)d_out);
}